// Round 10
// baseline (170.246 us; speedup 1.0000x reference)
//
#include <hip/hip_runtime.h>
#include <hip/hip_bf16.h>
#include <stdint.h>

#define B_ 8
#define L_ 2048
#define D_ 1024
#define N_ 16
#define M_ (B_ * L_)   // 16384 rows
#define K_ D_          // 1024
#define SEG_ 64
#define SLEN_ (L_ / SEG_)   // 32
#define LOG2E 1.44269504088896341f

typedef __bf16 bf16;
typedef __bf16 bf16x8 __attribute__((ext_vector_type(8)));
typedef float f32x4 __attribute__((ext_vector_type(4)));

// ---------------- f32 -> bf16 conversion (vectorized x4) ----------------
__global__ __launch_bounds__(256) void cvt_f32_bf16(const float* __restrict__ in,
                                                    bf16* __restrict__ out, int n4) {
  int i = blockIdx.x * 256 + threadIdx.x;
  const int stride = gridDim.x * 256;
  const float4* in4 = (const float4*)in;
  uint2* out2 = (uint2*)out;
  for (; i < n4; i += stride) {
    float4 v = in4[i];
    union { bf16 h[4]; uint2 u; } p;
    p.h[0] = (bf16)v.x; p.h[1] = (bf16)v.y; p.h[2] = (bf16)v.z; p.h[3] = (bf16)v.w;
    out2[i] = p.u;
  }
}

// ---------------- async global->LDS helper (16B) ----------------
__device__ inline void gload_lds16(const bf16* g, bf16* l) {
  __builtin_amdgcn_global_load_lds(
      (const __attribute__((address_space(1))) void*)g,
      (__attribute__((address_space(3))) void*)l, 16, 0, 0);
}

__device__ inline float softplus_f(float z) {
  return fmaxf(z, 0.f) + __logf(1.f + __expf(-fabsf(z)));
}

// ---------------- dt GEMM: dtb = bf16(softplus(Xb @ Wdb^T + bd)) ----------------
// 128x128 tile, BK=32, 4 waves (2x2). Double-buffered, both-sides LDS XOR-swizzle,
// XCD-chunked block swizzle. (R8-proven 2-phase version: 54.5 us)
__global__ __launch_bounds__(256) void gemm_dt(const bf16* __restrict__ Xb,
                                               const bf16* __restrict__ Wdb,
                                               const float* __restrict__ bd,
                                               bf16* __restrict__ dtb) {
  __shared__ bf16 As[2][128 * 32];
  __shared__ bf16 Bs[2][128 * 32];
  const int tid = threadIdx.x;
  const int lane = tid & 63;
  const int wave = tid >> 6;
  const int wr = wave >> 1, wc = wave & 1;
  const int virt = (blockIdx.x & 7) * 128 + (blockIdx.x >> 3);
  const int mt = virt >> 3, nt = virt & 7;
  const int m0 = mt * 128, n0 = nt * 128;

  const bf16* ga[2];
  const bf16* gb[2];
#pragma unroll
  for (int q = 0; q < 2; ++q) {
    const int c = tid + 256 * q;
    const int row = c >> 2;
    const int col8 = ((c & 3) ^ (row & 3)) * 8;
    ga[q] = Xb + (size_t)(m0 + row) * K_ + col8;
    gb[q] = Wdb + (size_t)(n0 + row) * K_ + col8;
  }

  f32x4 acc[4][4] = {};
  const int frow = (lane & 15);
  const int khalf = (lane >> 4);   // 0..3

  int aoff[4], boff[4];
#pragma unroll
  for (int i = 0; i < 4; ++i) {
    const int Ra = wr * 64 + i * 16 + frow;
    const int Rb = wc * 64 + i * 16 + frow;
    aoff[i] = Ra * 32 + (khalf ^ (Ra & 3)) * 8;
    boff[i] = Rb * 32 + (khalf ^ (Rb & 3)) * 8;
  }

#define STAGE_(buf, kt)                                         \
  {                                                             \
    gload_lds16(ga[0] + (kt), &As[buf][tid * 8]);               \
    gload_lds16(ga[1] + (kt), &As[buf][(tid + 256) * 8]);       \
    gload_lds16(gb[0] + (kt), &Bs[buf][tid * 8]);               \
    gload_lds16(gb[1] + (kt), &Bs[buf][(tid + 256) * 8]);       \
  }

  STAGE_(0, 0);
  __syncthreads();

  int cur = 0;
  for (int t = 0; t < K_ / 32; ++t) {
    if (t + 1 < K_ / 32) STAGE_(cur ^ 1, (t + 1) * 32);
    bf16x8 af[4], bfr[4];
#pragma unroll
    for (int i = 0; i < 4; ++i) af[i] = *(const bf16x8*)&As[cur][aoff[i]];
#pragma unroll
    for (int i = 0; i < 4; ++i) bfr[i] = *(const bf16x8*)&Bs[cur][boff[i]];
#pragma unroll
    for (int i = 0; i < 4; ++i)
#pragma unroll
      for (int j = 0; j < 4; ++j)
        acc[i][j] = __builtin_amdgcn_mfma_f32_16x16x32_bf16(af[i], bfr[j], acc[i][j], 0, 0, 0);
    __syncthreads();
    cur ^= 1;
  }
#undef STAGE_

  const int rbase = m0 + wr * 64 + (lane >> 4) * 4;
  const int cbase = n0 + wc * 64 + (lane & 15);
#pragma unroll
  for (int j = 0; j < 4; ++j) {
    const int col = cbase + j * 16;
    const float bias = bd[col];
#pragma unroll
    for (int i = 0; i < 4; ++i) {
      const int row = rbase + i * 16;
#pragma unroll
      for (int r = 0; r < 4; ++r) {
        float z = acc[i][j][r] + bias;
        dtb[(size_t)(row + r) * D_ + col] = (bf16)softplus_f(z);
      }
    }
  }
}

// ---------------- Bx = x @ Wb^T via MFMA ([M_,16]) ----------------
__global__ __launch_bounds__(256) void bx_mfma(const bf16* __restrict__ Xb,
                                               const bf16* __restrict__ Wbb,
                                               float* __restrict__ Bx) {
  const int lane = threadIdx.x & 63;
  const int wave = threadIdx.x >> 6;
  const int row0 = blockIdx.x * 64 + wave * 16;
  const int fr = lane & 15;
  const int kg = (lane >> 4) * 8;
  const bf16* ga = Xb + (size_t)(row0 + fr) * K_ + kg;
  const bf16* gb = Wbb + (size_t)fr * K_ + kg;
  f32x4 acc = {};
#pragma unroll 8
  for (int kt = 0; kt < K_; kt += 32) {
    bf16x8 af = *(const bf16x8*)(ga + kt);
    bf16x8 bf = *(const bf16x8*)(gb + kt);
    acc = __builtin_amdgcn_mfma_f32_16x16x32_bf16(af, bf, acc, 0, 0, 0);
  }
  const int orow = row0 + (lane >> 4) * 4;
  const int ocol = lane & 15;
#pragma unroll
  for (int r = 0; r < 4; ++r)
    Bx[(size_t)(orow + r) * N_ + ocol] = acc[r];
}

// ---------------- pass 1: per-segment summaries only ----------------
__global__ __launch_bounds__(256) void scan_p1(
    const bf16* __restrict__ dtb, const float* __restrict__ Bx,
    const float* __restrict__ A, bf16* __restrict__ hseg,
    float* __restrict__ stot) {
  const int tid = threadIdx.x;
  const int bi = blockIdx.x;
  const int seg = bi & 63;
  const int dtile = (bi >> 6) & 3;
  const int b = bi >> 8;
  const int d = dtile * 256 + tid;
  const int l0 = seg * SLEN_;

  const float* bxp = Bx + ((size_t)b * L_ + l0) * N_;   // wave-uniform

  float A2[N_];
  {
    const float4* ap = (const float4*)(A + (size_t)d * N_);
#pragma unroll
    for (int q = 0; q < 4; ++q) {
      float4 a = ap[q];
      A2[q * 4 + 0] = a.x * LOG2E; A2[q * 4 + 1] = a.y * LOG2E;
      A2[q * 4 + 2] = a.z * LOG2E; A2[q * 4 + 3] = a.w * LOG2E;
    }
  }

  const bf16* dtp = dtb + ((size_t)b * L_ + l0) * D_ + d;
  float h[N_] = {};
  float s = 0.f;

  float cdt[4];
#pragma unroll
  for (int u = 0; u < 4; ++u) cdt[u] = (float)dtp[(size_t)u * D_];

#define P1_STEP(i, c0)                                              \
  {                                                                 \
    s += (c0);                                                      \
    _Pragma("unroll")                                               \
    for (int q = 0; q < 4; ++q) {                                   \
      const float4 bv = *(const float4*)(bxp + (i) * N_ + q * 4);   \
      const float bvf[4] = {bv.x, bv.y, bv.z, bv.w};                \
      _Pragma("unroll")                                             \
      for (int j = 0; j < 4; ++j) {                                 \
        const int n = q * 4 + j;                                    \
        const float e = __builtin_amdgcn_exp2f((c0) * A2[n]);       \
        h[n] = fmaf(e, h[n], (c0) * bvf[j]);                        \
      }                                                             \
    }                                                               \
  }

  for (int i0 = 0; i0 < SLEN_ - 4; i0 += 4) {
#pragma unroll
    for (int u = 0; u < 4; ++u) {
      const int i = i0 + u;
      const float c0 = cdt[u];
      cdt[u] = (float)dtp[(size_t)(i + 4) * D_];
      P1_STEP(i, c0);
    }
  }
#pragma unroll
  for (int u = 0; u < 4; ++u) {
    const int i = SLEN_ - 4 + u;
    P1_STEP(i, cdt[u]);
  }
#undef P1_STEP

  bf16* hp = hseg + (((size_t)b * SEG_ + seg) * D_ + d) * N_;
  union { bf16 v[16]; uint4 u[2]; } pk;
#pragma unroll
  for (int n = 0; n < N_; ++n) pk.v[n] = (bf16)h[n];
  ((uint4*)hp)[0] = pk.u[0];
  ((uint4*)hp)[1] = pk.u[1];
  stot[((size_t)b * SEG_ + seg) * D_ + d] = s;
}

// ---------------- pass 2: exclusive-prefix combine (in-place hseg -> h0) ----
__global__ __launch_bounds__(256) void scan_combine(
    const float* __restrict__ A, bf16* __restrict__ hseg,
    const float* __restrict__ stot) {
  const int tid = threadIdx.x;
  const int bi = blockIdx.x;          // B_ * (D_/16) = 512
  const int b = bi >> 6;
  const int d = (bi & 63) * 16 + (tid >> 4);
  const int n = tid & 15;
  const float A2 = A[(size_t)d * N_ + n] * LOG2E;

  const size_t hbase = ((size_t)b * SEG_ * D_ + d) * N_ + n;
  const size_t sbase = (size_t)b * SEG_ * D_ + d;
  float g = 0.f;
  float hs = (float)hseg[hbase];
  float st = stot[sbase];
  for (int sg = 0; sg < SEG_; ++sg) {
    const int s1 = (sg + 1 < SEG_) ? sg + 1 : sg;
    const float nhs = (float)hseg[hbase + (size_t)s1 * D_ * N_];
    const float nst = stot[sbase + (size_t)s1 * D_];
    hseg[hbase + (size_t)sg * D_ * N_] = (bf16)g;
    g = fmaf(__builtin_amdgcn_exp2f(A2 * st), g, hs);
    hs = nhs; st = nst;
  }
}

// ---------------- pass 3: full recurrence from h0, single out write ----------
// bx via uniform pointer; 4-deep dt/x register prefetch (covers L3 latency).
__global__ __launch_bounds__(256) void scan_p3(
    const bf16* __restrict__ dtb, const float* __restrict__ Bx,
    const bf16* __restrict__ xb, const float* __restrict__ A,
    const float* __restrict__ C, const float* __restrict__ Dp,
    const bf16* __restrict__ hseg, float* __restrict__ out) {
  const int tid = threadIdx.x;
  const int bi = blockIdx.x;
  const int seg = bi & 63;
  const int dtile = (bi >> 6) & 3;
  const int b = bi >> 8;
  const int d = dtile * 256 + tid;
  const int l0 = seg * SLEN_;

  const float* bxp = Bx + ((size_t)b * L_ + l0) * N_;   // wave-uniform

  float A2[N_], Cv[N_], h[N_];
  {
    const float4* ap = (const float4*)(A + (size_t)d * N_);
    const float4* cp = (const float4*)(C + (size_t)d * N_);
    const bf16* hp = hseg + (((size_t)b * SEG_ + seg) * D_ + d) * N_;
    union { uint4 u[2]; bf16 v[16]; } pk;
    pk.u[0] = ((const uint4*)hp)[0];
    pk.u[1] = ((const uint4*)hp)[1];
#pragma unroll
    for (int q = 0; q < 4; ++q) {
      float4 a = ap[q], c = cp[q];
      A2[q * 4 + 0] = a.x * LOG2E; A2[q * 4 + 1] = a.y * LOG2E;
      A2[q * 4 + 2] = a.z * LOG2E; A2[q * 4 + 3] = a.w * LOG2E;
      Cv[q * 4 + 0] = c.x; Cv[q * 4 + 1] = c.y;
      Cv[q * 4 + 2] = c.z; Cv[q * 4 + 3] = c.w;
    }
#pragma unroll
    for (int n = 0; n < N_; ++n) h[n] = (float)pk.v[n];
  }
  const float Dpv = Dp[d];

  const size_t base = ((size_t)b * L_ + l0) * D_ + d;
  const bf16* dtp = dtb + base;
  const bf16* xp = xb + base;
  float* op = out + base;

  float cdt[4], cx[4];
#pragma unroll
  for (int u = 0; u < 4; ++u) {
    cdt[u] = (float)dtp[(size_t)u * D_];
    cx[u]  = (float)xp[(size_t)u * D_];
  }

#define P3_STEP(i, c0, x0)                                          \
  {                                                                 \
    float y = Dpv * (x0);                                           \
    _Pragma("unroll")                                               \
    for (int q = 0; q < 4; ++q) {                                   \
      const float4 bv = *(const float4*)(bxp + (i) * N_ + q * 4);   \
      const float bvf[4] = {bv.x, bv.y, bv.z, bv.w};                \
      _Pragma("unroll")                                             \
      for (int j = 0; j < 4; ++j) {                                 \
        const int n = q * 4 + j;                                    \
        const float e = __builtin_amdgcn_exp2f((c0) * A2[n]);       \
        h[n] = fmaf(e, h[n], (c0) * bvf[j]);                        \
        y = fmaf(h[n], Cv[n], y);                                   \
      }                                                             \
    }                                                               \
    op[(size_t)(i) * D_] = y;                                       \
  }

  for (int i0 = 0; i0 < SLEN_ - 4; i0 += 4) {
#pragma unroll
    for (int u = 0; u < 4; ++u) {
      const int i = i0 + u;
      const float c0 = cdt[u], x0 = cx[u];
      cdt[u] = (float)dtp[(size_t)(i + 4) * D_];
      cx[u]  = (float)xp[(size_t)(i + 4) * D_];
      P3_STEP(i, c0, x0);
    }
  }
#pragma unroll
  for (int u = 0; u < 4; ++u) {
    const int i = SLEN_ - 4 + u;
    P3_STEP(i, cdt[u], cx[u]);
  }
#undef P3_STEP
}

// ---------------- launch ----------------
extern "C" void kernel_launch(void* const* d_in, const int* in_sizes, int n_in,
                              void* d_out, int out_size, void* d_ws, size_t ws_size,
                              hipStream_t stream) {
  const float* x  = (const float*)d_in[0];
  const float* A  = (const float*)d_in[1];
  const float* Wb = (const float*)d_in[2];
  const float* C  = (const float*)d_in[3];
  const float* Dp = (const float*)d_in[4];
  const float* Wd = (const float*)d_in[5];
  const float* bd = (const float*)d_in[6];
  float* out = (float*)d_out;

  char* ws = (char*)d_ws;
  bf16*  dtb  = (bf16*)ws;                                  // 32 MB [M,D] bf16
  bf16*  xb   = (bf16*)(ws + (size_t)33554432);             // 32 MB [M,K] bf16
  bf16*  wdb  = (bf16*)(ws + (size_t)67108864);             //  2 MB [D,K] bf16
  bf16*  wbb  = (bf16*)(ws + (size_t)69206016);             // 32 KB [16,K] bf16
  float* bx   = (float*)(ws + (size_t)69238784);            //  1 MB [M,16] f32
  bf16*  hseg = (bf16*)(ws + (size_t)70287360);             // 16 MB [B][SEG][D][N] bf16
  float* stot = (float*)(ws + (size_t)87064576);            //  2 MB [B][SEG][D] f32

  cvt_f32_bf16<<<2048, 256, 0, stream>>>(x, xb, M_ * K_ / 4);
  cvt_f32_bf16<<<1024, 256, 0, stream>>>(Wd, wdb, D_ * K_ / 4);
  cvt_f32_bf16<<<16, 256, 0, stream>>>(Wb, wbb, N_ * K_ / 4);
  bx_mfma<<<dim3(M_ / 64), 256, 0, stream>>>(xb, wbb, bx);
  gemm_dt<<<dim3((M_ / 128) * (D_ / 128)), 256, 0, stream>>>(xb, wdb, bd, dtb);
  scan_p1<<<dim3(B_ * 4 * SEG_), 256, 0, stream>>>(dtb, bx, A, hseg, stot);
  scan_combine<<<dim3(B_ * (D_ / 16)), 256, 0, stream>>>(A, hseg, stot);
  scan_p3<<<dim3(B_ * 4 * SEG_), 256, 0, stream>>>(dtb, bx, xb, A, C, Dp, hseg, out);
}

// Round 11
// 166.218 us; speedup vs baseline: 1.0242x; 1.0242x over previous
//
#include <hip/hip_runtime.h>
#include <hip/hip_bf16.h>
#include <stdint.h>

#define B_ 8
#define L_ 2048
#define D_ 1024
#define N_ 16
#define M_ (B_ * L_)   // 16384 rows
#define K_ D_          // 1024
#define SEG_ 64
#define SLEN_ (L_ / SEG_)   // 32
#define LOG2E 1.44269504088896341f

typedef __bf16 bf16;
typedef __bf16 bf16x8 __attribute__((ext_vector_type(8)));
typedef float f32x4 __attribute__((ext_vector_type(4)));

// ---------------- f32 -> bf16 conversion (vectorized x4) ----------------
__global__ __launch_bounds__(256) void cvt_f32_bf16(const float* __restrict__ in,
                                                    bf16* __restrict__ out, int n4) {
  int i = blockIdx.x * 256 + threadIdx.x;
  const int stride = gridDim.x * 256;
  const float4* in4 = (const float4*)in;
  uint2* out2 = (uint2*)out;
  for (; i < n4; i += stride) {
    float4 v = in4[i];
    union { bf16 h[4]; uint2 u; } p;
    p.h[0] = (bf16)v.x; p.h[1] = (bf16)v.y; p.h[2] = (bf16)v.z; p.h[3] = (bf16)v.w;
    out2[i] = p.u;
  }
}

// ---------------- async global->LDS helper (16B) ----------------
__device__ inline void gload_lds16(const bf16* g, bf16* l) {
  __builtin_amdgcn_global_load_lds(
      (const __attribute__((address_space(1))) void*)g,
      (__attribute__((address_space(3))) void*)l, 16, 0, 0);
}

__device__ inline float softplus_f(float z) {
  return fmaxf(z, 0.f) + __logf(1.f + __expf(-fabsf(z)));
}

// ---------------- dt GEMM: dtb = bf16(softplus(Xb @ Wdb^T + bd)) ----------------
// 256x256 tile, 8-phase counted-vmcnt schedule (T3+T4), dispersal swizzle (T2),
// setprio (T5), XCD-chunked swizzle (T1). 512 thr = 8 waves (2M x 4N).
// __launch_bounds__(512, 2): 2 waves/EU min -> VGPR cap 256 (R9 failed at the
// default cap 124: acc needs 128 -> spill; WRITE_SIZE showed +35 MB scratch).
// vmcnt ledger (2 loads/thread/half-tile, order A-kh0,B-kh0,A-kh1,B-kh1):
//   at waits: 10 outstanding, drain oldest 4 -> vmcnt(6); tail tile: 8 -> 4 -> 0.
__global__ __launch_bounds__(512, 2) void gemm_dt(const bf16* __restrict__ Xb,
                                                  const bf16* __restrict__ Wdb,
                                                  const float* __restrict__ bd,
                                                  bf16* __restrict__ dtb) {
  __shared__ bf16 SA[2][2][256 * 32];
  __shared__ bf16 SB[2][2][256 * 32];
  const int tid = threadIdx.x;
  const int lane = tid & 63;
  const int wave = tid >> 6;      // 0..7
  const int wr = wave >> 2;       // 0..1  (M half)
  const int wc = wave & 3;        // 0..3  (N quarter)
  const int virt = (blockIdx.x & 7) * 32 + (blockIdx.x >> 3);
  const int mt = virt >> 2, nt = virt & 3;
  const int m0 = mt * 256, n0 = nt * 256;

  const bf16* gA[2];
  const bf16* gB[2];
  int ldst[2];
#pragma unroll
  for (int q = 0; q < 2; ++q) {
    const int cc = tid + 512 * q;
    const int row = cc >> 2, c = cc & 3;
    const int sk = (c ^ ((row >> 1) & 3)) * 8;
    gA[q] = Xb + (size_t)(m0 + row) * K_ + sk;
    gB[q] = Wdb + (size_t)(n0 + row) * K_ + sk;
    ldst[q] = cc * 8;
  }

#define STA(bf_, kh_, kt_)                                              \
  { gload_lds16(gA[0] + (kt_) * 64 + (kh_) * 32, &SA[bf_][kh_][ldst[0]]); \
    gload_lds16(gA[1] + (kt_) * 64 + (kh_) * 32, &SA[bf_][kh_][ldst[1]]); }
#define STB(bf_, kh_, kt_)                                              \
  { gload_lds16(gB[0] + (kt_) * 64 + (kh_) * 32, &SB[bf_][kh_][ldst[0]]); \
    gload_lds16(gB[1] + (kt_) * 64 + (kh_) * 32, &SB[bf_][kh_][ldst[1]]); }

  const int fr = lane & 15;
  const int kq = lane >> 4;       // 16B chunk 0..3
  int aoff[8], boff[4];
#pragma unroll
  for (int i = 0; i < 8; ++i) {
    const int R = wr * 128 + i * 16 + fr;
    aoff[i] = R * 32 + ((kq ^ ((R >> 1) & 3)) * 8);
  }
#pragma unroll
  for (int j = 0; j < 4; ++j) {
    const int R = wc * 64 + j * 16 + fr;
    boff[j] = R * 32 + ((kq ^ ((R >> 1) & 3)) * 8);
  }

  f32x4 acc[8][4] = {};
  bf16x8 a[8];

#define MF(d_, av_, bv_) d_ = __builtin_amdgcn_mfma_f32_16x16x32_bf16(av_, bv_, d_, 0, 0, 0)

#define PH_A(bf_, kh_)                                                  \
  {                                                                     \
    _Pragma("unroll")                                                   \
    for (int i = 0; i < 8; ++i) a[i] = *(const bf16x8*)&SA[bf_][kh_][aoff[i]]; \
    bf16x8 b0 = *(const bf16x8*)&SB[bf_][kh_][boff[0]];                 \
    bf16x8 b1 = *(const bf16x8*)&SB[bf_][kh_][boff[1]];                 \
    __builtin_amdgcn_s_setprio(1);                                      \
    _Pragma("unroll")                                                   \
    for (int i = 0; i < 8; ++i) { MF(acc[i][0], a[i], b0); MF(acc[i][1], a[i], b1); } \
    __builtin_amdgcn_s_setprio(0);                                      \
    __builtin_amdgcn_s_barrier();                                       \
  }
#define PH_B(bf_, kh_)                                                  \
  {                                                                     \
    bf16x8 b2 = *(const bf16x8*)&SB[bf_][kh_][boff[2]];                 \
    bf16x8 b3 = *(const bf16x8*)&SB[bf_][kh_][boff[3]];                 \
    __builtin_amdgcn_s_setprio(1);                                      \
    _Pragma("unroll")                                                   \
    for (int i = 0; i < 8; ++i) { MF(acc[i][2], a[i], b2); MF(acc[i][3], a[i], b3); } \
    __builtin_amdgcn_s_setprio(0);                                      \
    __builtin_amdgcn_s_barrier();                                       \
  }

#define TILE(bf_, nb_, t_, STG_)                                        \
  {                                                                     \
    if (STG_) { STA(nb_, 0, (t_) + 1); }                                \
    if (STG_) { asm volatile("s_waitcnt vmcnt(6)" ::: "memory"); }      \
    else      { asm volatile("s_waitcnt vmcnt(4)" ::: "memory"); }      \
    __builtin_amdgcn_s_barrier();                                       \
    PH_A(bf_, 0)                                                        \
    if (STG_) { STB(nb_, 0, (t_) + 1); }                                \
    PH_B(bf_, 0)                                                        \
    if (STG_) { STA(nb_, 1, (t_) + 1); }                                \
    if (STG_) { asm volatile("s_waitcnt vmcnt(6)" ::: "memory"); }      \
    else      { asm volatile("s_waitcnt vmcnt(0)" ::: "memory"); }      \
    __builtin_amdgcn_s_barrier();                                       \
    PH_A(bf_, 1)                                                        \
    if (STG_) { STB(nb_, 1, (t_) + 1); }                                \
    PH_B(bf_, 1)                                                        \
  }

  // prologue: tile 0 -> buf 0 (order defines vmcnt drain order)
  STA(0, 0, 0); STB(0, 0, 0); STA(0, 1, 0); STB(0, 1, 0);

#pragma unroll 1
  for (int t2 = 0; t2 < 8; ++t2) {
    TILE(0, 1, 2 * t2, true)
    TILE(1, 0, 2 * t2 + 1, (t2 < 7))
  }
#undef TILE
#undef PH_A
#undef PH_B
#undef MF
#undef STA
#undef STB

  // epilogue: C/D layout col=lane&15, row=(lane>>4)*4+r
  const int rb = m0 + wr * 128 + (lane >> 4) * 4;
  const int cb = n0 + wc * 64 + (lane & 15);
#pragma unroll
  for (int j = 0; j < 4; ++j) {
    const int col = cb + j * 16;
    const float bias = bd[col];
#pragma unroll
    for (int i = 0; i < 8; ++i) {
      const int row = rb + i * 16;
#pragma unroll
      for (int r = 0; r < 4; ++r)
        dtb[(size_t)(row + r) * D_ + col] = (bf16)softplus_f(acc[i][j][r] + bias);
    }
  }
}

// ---------------- Bx = x @ Wb^T via MFMA ([M_,16]) ----------------
__global__ __launch_bounds__(256) void bx_mfma(const bf16* __restrict__ Xb,
                                               const bf16* __restrict__ Wbb,
                                               float* __restrict__ Bx) {
  const int lane = threadIdx.x & 63;
  const int wave = threadIdx.x >> 6;
  const int row0 = blockIdx.x * 64 + wave * 16;
  const int fr = lane & 15;
  const int kg = (lane >> 4) * 8;
  const bf16* ga = Xb + (size_t)(row0 + fr) * K_ + kg;
  const bf16* gb = Wbb + (size_t)fr * K_ + kg;
  f32x4 acc = {};
#pragma unroll 8
  for (int kt = 0; kt < K_; kt += 32) {
    bf16x8 af = *(const bf16x8*)(ga + kt);
    bf16x8 bf = *(const bf16x8*)(gb + kt);
    acc = __builtin_amdgcn_mfma_f32_16x16x32_bf16(af, bf, acc, 0, 0, 0);
  }
  const int orow = row0 + (lane >> 4) * 4;
  const int ocol = lane & 15;
#pragma unroll
  for (int r = 0; r < 4; ++r)
    Bx[(size_t)(orow + r) * N_ + ocol] = acc[r];
}

// ---------------- pass 1: per-segment summaries only ----------------
__global__ __launch_bounds__(256) void scan_p1(
    const bf16* __restrict__ dtb, const float* __restrict__ Bx,
    const float* __restrict__ A, bf16* __restrict__ hseg,
    float* __restrict__ stot) {
  const int tid = threadIdx.x;
  const int bi = blockIdx.x;
  const int seg = bi & 63;
  const int dtile = (bi >> 6) & 3;
  const int b = bi >> 8;
  const int d = dtile * 256 + tid;
  const int l0 = seg * SLEN_;

  const float* bxp = Bx + ((size_t)b * L_ + l0) * N_;   // wave-uniform

  float A2[N_];
  {
    const float4* ap = (const float4*)(A + (size_t)d * N_);
#pragma unroll
    for (int q = 0; q < 4; ++q) {
      float4 a = ap[q];
      A2[q * 4 + 0] = a.x * LOG2E; A2[q * 4 + 1] = a.y * LOG2E;
      A2[q * 4 + 2] = a.z * LOG2E; A2[q * 4 + 3] = a.w * LOG2E;
    }
  }

  const bf16* dtp = dtb + ((size_t)b * L_ + l0) * D_ + d;
  float h[N_] = {};
  float s = 0.f;

  float cdt[4];
#pragma unroll
  for (int u = 0; u < 4; ++u) cdt[u] = (float)dtp[(size_t)u * D_];

#define P1_STEP(i, c0)                                              \
  {                                                                 \
    s += (c0);                                                      \
    _Pragma("unroll")                                               \
    for (int q = 0; q < 4; ++q) {                                   \
      const float4 bv = *(const float4*)(bxp + (i) * N_ + q * 4);   \
      const float bvf[4] = {bv.x, bv.y, bv.z, bv.w};                \
      _Pragma("unroll")                                             \
      for (int j = 0; j < 4; ++j) {                                 \
        const int n = q * 4 + j;                                    \
        const float e = __builtin_amdgcn_exp2f((c0) * A2[n]);       \
        h[n] = fmaf(e, h[n], (c0) * bvf[j]);                        \
      }                                                             \
    }                                                               \
  }

  for (int i0 = 0; i0 < SLEN_ - 4; i0 += 4) {
#pragma unroll
    for (int u = 0; u < 4; ++u) {
      const int i = i0 + u;
      const float c0 = cdt[u];
      cdt[u] = (float)dtp[(size_t)(i + 4) * D_];
      P1_STEP(i, c0);
    }
  }
#pragma unroll
  for (int u = 0; u < 4; ++u) {
    const int i = SLEN_ - 4 + u;
    P1_STEP(i, cdt[u]);
  }
#undef P1_STEP

  bf16* hp = hseg + (((size_t)b * SEG_ + seg) * D_ + d) * N_;
  union { bf16 v[16]; uint4 u[2]; } pk;
#pragma unroll
  for (int n = 0; n < N_; ++n) pk.v[n] = (bf16)h[n];
  ((uint4*)hp)[0] = pk.u[0];
  ((uint4*)hp)[1] = pk.u[1];
  stot[((size_t)b * SEG_ + seg) * D_ + d] = s;
}

// ---------------- pass 2: exclusive-prefix combine (in-place hseg -> h0) ----
__global__ __launch_bounds__(256) void scan_combine(
    const float* __restrict__ A, bf16* __restrict__ hseg,
    const float* __restrict__ stot) {
  const int tid = threadIdx.x;
  const int bi = blockIdx.x;          // B_ * (D_/16) = 512
  const int b = bi >> 6;
  const int d = (bi & 63) * 16 + (tid >> 4);
  const int n = tid & 15;
  const float A2 = A[(size_t)d * N_ + n] * LOG2E;

  const size_t hbase = ((size_t)b * SEG_ * D_ + d) * N_ + n;
  const size_t sbase = (size_t)b * SEG_ * D_ + d;
  float g = 0.f;
  float hs = (float)hseg[hbase];
  float st = stot[sbase];
  for (int sg = 0; sg < SEG_; ++sg) {
    const int s1 = (sg + 1 < SEG_) ? sg + 1 : sg;
    const float nhs = (float)hseg[hbase + (size_t)s1 * D_ * N_];
    const float nst = stot[sbase + (size_t)s1 * D_];
    hseg[hbase + (size_t)sg * D_ * N_] = (bf16)g;
    g = fmaf(__builtin_amdgcn_exp2f(A2 * st), g, hs);
    hs = nhs; st = nst;
  }
}

// ---------------- pass 3: full recurrence from h0, single out write ----------
// bx via uniform pointer; 4-deep dt/x register prefetch (covers L3 latency).
__global__ __launch_bounds__(256) void scan_p3(
    const bf16* __restrict__ dtb, const float* __restrict__ Bx,
    const bf16* __restrict__ xb, const float* __restrict__ A,
    const float* __restrict__ C, const float* __restrict__ Dp,
    const bf16* __restrict__ hseg, float* __restrict__ out) {
  const int tid = threadIdx.x;
  const int bi = blockIdx.x;
  const int seg = bi & 63;
  const int dtile = (bi >> 6) & 3;
  const int b = bi >> 8;
  const int d = dtile * 256 + tid;
  const int l0 = seg * SLEN_;

  const float* bxp = Bx + ((size_t)b * L_ + l0) * N_;   // wave-uniform

  float A2[N_], Cv[N_], h[N_];
  {
    const float4* ap = (const float4*)(A + (size_t)d * N_);
    const float4* cp = (const float4*)(C + (size_t)d * N_);
    const bf16* hp = hseg + (((size_t)b * SEG_ + seg) * D_ + d) * N_;
    union { uint4 u[2]; bf16 v[16]; } pk;
    pk.u[0] = ((const uint4*)hp)[0];
    pk.u[1] = ((const uint4*)hp)[1];
#pragma unroll
    for (int q = 0; q < 4; ++q) {
      float4 a = ap[q], c = cp[q];
      A2[q * 4 + 0] = a.x * LOG2E; A2[q * 4 + 1] = a.y * LOG2E;
      A2[q * 4 + 2] = a.z * LOG2E; A2[q * 4 + 3] = a.w * LOG2E;
      Cv[q * 4 + 0] = c.x; Cv[q * 4 + 1] = c.y;
      Cv[q * 4 + 2] = c.z; Cv[q * 4 + 3] = c.w;
    }
#pragma unroll
    for (int n = 0; n < N_; ++n) h[n] = (float)pk.v[n];
  }
  const float Dpv = Dp[d];

  const size_t base = ((size_t)b * L_ + l0) * D_ + d;
  const bf16* dtp = dtb + base;
  const bf16* xp = xb + base;
  float* op = out + base;

  float cdt[4], cx[4];
#pragma unroll
  for (int u = 0; u < 4; ++u) {
    cdt[u] = (float)dtp[(size_t)u * D_];
    cx[u]  = (float)xp[(size_t)u * D_];
  }

#define P3_STEP(i, c0, x0)                                          \
  {                                                                 \
    float y = Dpv * (x0);                                           \
    _Pragma("unroll")                                               \
    for (int q = 0; q < 4; ++q) {                                   \
      const float4 bv = *(const float4*)(bxp + (i) * N_ + q * 4);   \
      const float bvf[4] = {bv.x, bv.y, bv.z, bv.w};                \
      _Pragma("unroll")                                             \
      for (int j = 0; j < 4; ++j) {                                 \
        const int n = q * 4 + j;                                    \
        const float e = __builtin_amdgcn_exp2f((c0) * A2[n]);       \
        h[n] = fmaf(e, h[n], (c0) * bvf[j]);                        \
        y = fmaf(h[n], Cv[n], y);                                   \
      }                                                             \
    }                                                               \
    op[(size_t)(i) * D_] = y;                                       \
  }

  for (int i0 = 0; i0 < SLEN_ - 4; i0 += 4) {
#pragma unroll
    for (int u = 0; u < 4; ++u) {
      const int i = i0 + u;
      const float c0 = cdt[u], x0 = cx[u];
      cdt[u] = (float)dtp[(size_t)(i + 4) * D_];
      cx[u]  = (float)xp[(size_t)(i + 4) * D_];
      P3_STEP(i, c0, x0);
    }
  }
#pragma unroll
  for (int u = 0; u < 4; ++u) {
    const int i = SLEN_ - 4 + u;
    P3_STEP(i, cdt[u], cx[u]);
  }
#undef P3_STEP
}

// ---------------- launch ----------------
extern "C" void kernel_launch(void* const* d_in, const int* in_sizes, int n_in,
                              void* d_out, int out_size, void* d_ws, size_t ws_size,
                              hipStream_t stream) {
  const float* x  = (const float*)d_in[0];
  const float* A  = (const float*)d_in[1];
  const float* Wb = (const float*)d_in[2];
  const float* C  = (const float*)d_in[3];
  const float* Dp = (const float*)d_in[4];
  const float* Wd = (const float*)d_in[5];
  const float* bd = (const float*)d_in[6];
  float* out = (float*)d_out;

  char* ws = (char*)d_ws;
  bf16*  dtb  = (bf16*)ws;                                  // 32 MB [M,D] bf16
  bf16*  xb   = (bf16*)(ws + (size_t)33554432);             // 32 MB [M,K] bf16
  bf16*  wdb  = (bf16*)(ws + (size_t)67108864);             //  2 MB [D,K] bf16
  bf16*  wbb  = (bf16*)(ws + (size_t)69206016);             // 32 KB [16,K] bf16
  float* bx   = (float*)(ws + (size_t)69238784);            //  1 MB [M,16] f32
  bf16*  hseg = (bf16*)(ws + (size_t)70287360);             // 16 MB [B][SEG][D][N] bf16
  float* stot = (float*)(ws + (size_t)87064576);            //  2 MB [B][SEG][D] f32

  cvt_f32_bf16<<<2048, 256, 0, stream>>>(x, xb, M_ * K_ / 4);
  cvt_f32_bf16<<<1024, 256, 0, stream>>>(Wd, wdb, D_ * K_ / 4);
  cvt_f32_bf16<<<16, 256, 0, stream>>>(Wb, wbb, N_ * K_ / 4);
  bx_mfma<<<dim3(M_ / 64), 256, 0, stream>>>(xb, wbb, bx);
  gemm_dt<<<dim3((M_ / 256) * (D_ / 256)), 512, 0, stream>>>(xb, wdb, bd, dtb);
  scan_p1<<<dim3(B_ * 4 * SEG_), 256, 0, stream>>>(dtb, bx, A, hseg, stot);
  scan_combine<<<dim3(B_ * (D_ / 16)), 256, 0, stream>>>(A, hseg, stot);
  scan_p3<<<dim3(B_ * 4 * SEG_), 256, 0, stream>>>(dtb, bx, xb, A, C, Dp, hseg, out);
}